// Round 5
// baseline (563.695 us; speedup 1.0000x reference)
//
#include <hip/hip_runtime.h>
#include <hip/hip_bf16.h>
#include <math.h>

#define QQ   10
#define CC   64
#define HWSZ 65536          // H*W
#define NPOS 655360         // Q*H*W
#define LL   64800          // L_H*L_W
#define KK   9

// ---------------------------------------------------------------------------
// ROUND 5 (= round 3/4 resubmit): attribution experiment. Source identical to
// round 2 except k_gather_out is launched TWICE (idempotent). dur_us delta
// vs 523.9 µs measures one k_gather_out execution.
// ---------------------------------------------------------------------------

__global__ __launch_bounds__(256) void k_mask_zero(uint4* __restrict__ m) {
  m[blockIdx.x * 256 + threadIdx.x] = make_uint4(0u, 0u, 0u, 0u);
}

__global__ __launch_bounds__(256) void k_mask_set(
    const int* __restrict__ idx, unsigned char* __restrict__ m) {
  const int i = blockIdx.x * 256 + threadIdx.x;
  if (i < LL * KK) m[idx[i]] = 1;   // benign same-value races
}

// ---------------------------------------------------------------------------
// Kernel 1: transpose x (bq, c, hw) -> xt (b, n, c) in BF16, fused per-n
// channel sum/max (float2 stats). Stores PREDICATED on mask[n] (~59% kept).
// ---------------------------------------------------------------------------
__global__ __launch_bounds__(256) void k_transpose_stats(
    const float* __restrict__ x, const unsigned char* __restrict__ mask,
    __hip_bfloat16* __restrict__ xt, float2* __restrict__ stats) {
  __shared__ float tile[64][65];   // [c][hw], +1 pad
  __shared__ float sred[4][64];
  __shared__ float mred[4][64];
  const int t    = threadIdx.x;
  const int lane = t & 63;
  const int wid  = t >> 6;
  const int hw_base = blockIdx.x * 64;
  const int bq = blockIdx.y;            // 0..19
  const float* xp = x + (size_t)bq * CC * HWSZ + hw_base;

#pragma unroll
  for (int i = 0; i < 4; ++i) {
    int linear = t + i * 256;           // 0..1023
    int row  = linear >> 4;             // channel
    int col4 = (linear & 15) << 2;      // hw offset
    const float4 v = *(const float4*)(xp + (size_t)row * HWSZ + col4);
    tile[row][col4 + 0] = v.x;
    tile[row][col4 + 1] = v.y;
    tile[row][col4 + 2] = v.z;
    tile[row][col4 + 3] = v.w;
  }
  __syncthreads();

  const int b = bq / QQ, q = bq % QQ;
  const size_t n_base = (size_t)q * HWSZ + hw_base;
  __hip_bfloat16* xtb = xt + (size_t)b * NPOS * CC;

  // Phase A: packed transposed store, 16 B/lane (8 bf16).
  const int c0  = (lane & 7) << 3;      // channel octet base
  const int sub = lane >> 3;            // position sub-offset 0..7
#pragma unroll
  for (int j = 0; j < 2; ++j) {
    const int p = wid * 16 + j * 8 + sub;
    if (mask[n_base + p]) {
      union { __hip_bfloat162 h; unsigned u; } q0, q1, q2, q3;
      q0.h = __float22bfloat162_rn(make_float2(tile[c0 + 0][p], tile[c0 + 1][p]));
      q1.h = __float22bfloat162_rn(make_float2(tile[c0 + 2][p], tile[c0 + 3][p]));
      q2.h = __float22bfloat162_rn(make_float2(tile[c0 + 4][p], tile[c0 + 5][p]));
      q3.h = __float22bfloat162_rn(make_float2(tile[c0 + 6][p], tile[c0 + 7][p]));
      uint4 pk; pk.x = q0.u; pk.y = q1.u; pk.z = q2.u; pk.w = q3.u;
      *(uint4*)(xtb + (n_base + p) * CC + c0) = pk;
    }
  }

  // Phase B: per-position channel sum/max (wave partials, wave 0 combines).
  {
    const int pos = lane;
    const int cc0 = wid * 16;
    float psum = tile[cc0][pos];
    float pmax = psum;
#pragma unroll
    for (int c = 1; c < 16; ++c) {
      const float v = tile[cc0 + c][pos];
      psum += v;
      pmax = fmaxf(pmax, v);
    }
    sred[wid][pos] = psum;
    mred[wid][pos] = pmax;
  }
  __syncthreads();
  if (wid == 0) {
    const int pos = lane;
    if (mask[n_base + pos]) {
      float2 sm;
      sm.x = sred[0][pos] + sred[1][pos] + sred[2][pos] + sred[3][pos];
      sm.y = fmaxf(fmaxf(mred[0][pos], mred[1][pos]),
                   fmaxf(mred[2][pos], mred[3][pos]));
      stats[(size_t)b * NPOS + n_base + pos] = sm;
    }
  }
}

// ---------------------------------------------------------------------------
// Kernel 2 (fused): per block = 32 l's of one batch. (identical to round 2)
// ---------------------------------------------------------------------------
__global__ __launch_bounds__(256) void k_gather_out(
    const __hip_bfloat16* __restrict__ xt, const float2* __restrict__ stats,
    const int* __restrict__ idx, const float* __restrict__ att_w,
    const float* __restrict__ att_b, const float* __restrict__ tc_w,
    const float* __restrict__ tc_b, float* __restrict__ out) {
  const int blk    = blockIdx.x;
  const int b      = blk / (LL / 32);
  const int l_base = (blk % (LL / 32)) * 32;
  const int t = threadIdx.x, lane = t & 63, wid = t >> 6;
  const int qw = lane >> 4;             // quarter-wave id 0..3
  const int lq = lane & 15;             // lane-in-quarter
  const int cb = lq << 2;               // channel base (4 channels per lane)
  __shared__ float  res[64][33];        // [c][l-in-block]
  __shared__ float2 nw[32][KK];         // .x = n (int bits), .y = att weight
  __shared__ float  sms[32][KK], smm[32][KK];
  __shared__ float  aw[2 * KK * KK + KK];

  if (t < 2 * KK * KK + KK)
    aw[t] = (t < 2 * KK * KK) ? att_w[t] : att_b[t - 2 * KK * KK];

  const float2* stb = stats + (size_t)b * NPOS;
  // step 1a
  for (int i = t; i < 32 * KK; i += 256) {
    const int ll = i / KK, k = i - ll * KK;
    const int n = idx[(l_base + ll) * KK + k];
    nw[ll][k].x = __int_as_float(n);
    const float2 sm = stb[n];
    sms[ll][k] = sm.x;
    smm[ll][k] = sm.y;
  }
  __syncthreads();

  // step 1b
  for (int i = t; i < 32 * KK; i += 256) {
    const int ll = i / KK, h = i - ll * KK;
    float logit = aw[2 * KK * KK + h];
#pragma unroll
    for (int k = 0; k < KK; ++k) {
      logit = fmaf(sms[ll][k] * (1.0f / 64.0f), aw[h * 2 * KK + k], logit);
      logit = fmaf(smm[ll][k], aw[h * 2 * KK + KK + k], logit);
    }
    nw[ll][h].y = 1.0f + 1.0f / (1.0f + __expf(-logit));
  }

  // per-lane tc weights for 4 owned channels (overlaps with step 1b)
  float tw[4][KK], tb[4];
#pragma unroll
  for (int i = 0; i < 4; ++i) {
#pragma unroll
    for (int k = 0; k < KK; ++k) tw[i][k] = tc_w[(cb + i) * KK + k];
    tb[i] = tc_b[cb + i];
  }
  __syncthreads();

  // step 2: weighted gather-reduce. Quarter-wave per l, 8 B/lane.
  const uint2* xtb2 = (const uint2*)xt + (size_t)b * NPOS * 16;
#pragma unroll
  for (int j = 0; j < 2; ++j) {
    const int ll = wid * 8 + j * 4 + qw;
    float2 pw[KK];
#pragma unroll
    for (int k = 0; k < KK; ++k) pw[k] = nw[ll][k];   // broadcast ds_read_b64
    uint2 u[KK];
#pragma unroll
    for (int k = 0; k < KK; ++k)
      u[k] = xtb2[(size_t)__float_as_int(pw[k].x) * 16 + lq];
    float a0 = 0.f, a1 = 0.f, a2 = 0.f, a3 = 0.f;
#pragma unroll
    for (int k = 0; k < KK; ++k) {
      const float wk = pw[k].y;
      a0 = fmaf(wk * tw[0][k], __uint_as_float(u[k].x << 16), a0);
      a1 = fmaf(wk * tw[1][k], __uint_as_float(u[k].x & 0xffff0000u), a1);
      a2 = fmaf(wk * tw[2][k], __uint_as_float(u[k].y << 16), a2);
      a3 = fmaf(wk * tw[3][k], __uint_as_float(u[k].y & 0xffff0000u), a3);
    }
    res[cb + 0][ll] = a0 + tb[0];
    res[cb + 1][ll] = a1 + tb[1];
    res[cb + 2][ll] = a2 + tb[2];
    res[cb + 3][ll] = a3 + tb[3];
  }
  __syncthreads();

  // step 3: 64c x 32l tile out, float4 per store, 2 per thread.
  const int c  = t >> 2;
  const int q4 = t & 3;
#pragma unroll
  for (int rep = 0; rep < 2; ++rep) {
    const int lo = rep * 16 + q4 * 4;
    float4 o;
    o.x = res[c][lo + 0];
    o.y = res[c][lo + 1];
    o.z = res[c][lo + 2];
    o.w = res[c][lo + 3];
    *(float4*)(out + ((size_t)b * CC + c) * LL + l_base + lo) = o;
  }
}

extern "C" void kernel_launch(void* const* d_in, const int* in_sizes, int n_in,
                              void* d_out, int out_size, void* d_ws, size_t ws_size,
                              hipStream_t stream) {
  const float* x     = (const float*)d_in[0];
  const int*   idx   = (const int*)d_in[1];
  const float* att_w = (const float*)d_in[2];
  const float* att_b = (const float*)d_in[3];
  const float* tc_w  = (const float*)d_in[4];
  const float* tc_b  = (const float*)d_in[5];
  float* out = (float*)d_out;

  // ws carve: xt bf16 (2*N*64, 168 MB) | stats float2 (2*N, 10.5 MB)
  //           | mask (N bytes, 0.65 MB)
  __hip_bfloat16* xt = (__hip_bfloat16*)d_ws;
  float2* stats = (float2*)(xt + (size_t)2 * NPOS * CC);
  unsigned char* mask = (unsigned char*)(stats + (size_t)2 * NPOS);

  k_mask_zero<<<NPOS / (16 * 256), 256, 0, stream>>>((uint4*)mask);
  k_mask_set<<<(LL * KK + 255) / 256, 256, 0, stream>>>(idx, mask);

  dim3 g1(HWSZ / 64, 2 * QQ);
  k_transpose_stats<<<g1, 256, 0, stream>>>(x, mask, xt, stats);

  dim3 g2(2 * (LL / 32));
  // ATTRIBUTION: double-launch (idempotent). Δdur vs round 2 = one K2 exec.
  k_gather_out<<<g2, 256, 0, stream>>>(xt, stats, idx, att_w, att_b,
                                       tc_w, tc_b, out);
  k_gather_out<<<g2, 256, 0, stream>>>(xt, stats, idx, att_w, att_b,
                                       tc_w, tc_b, out);
}

// Round 6
// 517.748 us; speedup vs baseline: 1.0887x; 1.0887x over previous
//
#include <hip/hip_runtime.h>
#include <hip/hip_bf16.h>
#include <math.h>

#define QQ   10
#define CC   64
#define HWSZ 65536          // H*W
#define NPOS 655360         // Q*H*W
#define LL   64800          // L_H*L_W
#define KK   9
#define HT   128            // K1 hw-tile (was 64): 2x MLP, 512B segments

// ---------------------------------------------------------------------------
// Mask build: mask[n] = 1 iff n appears in idx. Batch-independent (idx shared).
// ---------------------------------------------------------------------------
__global__ __launch_bounds__(256) void k_mask_zero(uint4* __restrict__ m) {
  m[blockIdx.x * 256 + threadIdx.x] = make_uint4(0u, 0u, 0u, 0u);
}

__global__ __launch_bounds__(256) void k_mask_set(
    const int* __restrict__ idx, unsigned char* __restrict__ m) {
  const int i = blockIdx.x * 256 + threadIdx.x;
  if (i < LL * KK) m[idx[i]] = 1;   // benign same-value races
}

// ---------------------------------------------------------------------------
// Kernel 1: transpose x (bq, c, hw) -> xt (b, n, c) in BF16, fused per-n
// channel sum/max. ROUND 6: 64ch x 128hw tile (was 64x64) — 8 float4 loads
// in flight per thread, 512 B contiguous per wave-instr, half the blocks
// and barriers. LDS 37 KB -> 4 blocks/CU (16 waves/CU).
// ---------------------------------------------------------------------------
__global__ __launch_bounds__(256) void k_transpose_stats(
    const float* __restrict__ x, const unsigned char* __restrict__ mask,
    __hip_bfloat16* __restrict__ xt, float2* __restrict__ stats) {
  __shared__ float tile[64][HT + 1];   // [c][hw], +1 pad (33 KB)
  __shared__ float sred[4][HT];
  __shared__ float mred[4][HT];
  const int t    = threadIdx.x;
  const int lane = t & 63;
  const int wid  = t >> 6;
  const int hw_base = blockIdx.x * HT;
  const int bq = blockIdx.y;            // 0..19
  const float* xp = x + (size_t)bq * CC * HWSZ + hw_base;

  // Load 64 x 128 fp32: per wave-instr 2 rows x 512 B contiguous.
#pragma unroll
  for (int i = 0; i < 8; ++i) {
    int linear = t + i * 256;           // 0..2047
    int row  = linear >> 5;             // channel 0..63
    int col4 = (linear & 31) << 2;      // hw offset 0..124
    const float4 v = *(const float4*)(xp + (size_t)row * HWSZ + col4);
    tile[row][col4 + 0] = v.x;
    tile[row][col4 + 1] = v.y;
    tile[row][col4 + 2] = v.z;
    tile[row][col4 + 3] = v.w;
  }
  __syncthreads();

  const int b = bq / QQ, q = bq % QQ;
  const size_t n_base = (size_t)q * HWSZ + hw_base;
  __hip_bfloat16* xtb = xt + (size_t)b * NPOS * CC;

  // Phase A: packed transposed store, 16 B/lane (8 bf16), masked per row.
  const int c0  = (lane & 7) << 3;      // channel octet base
  const int sub = lane >> 3;            // position sub-offset 0..7
#pragma unroll
  for (int j = 0; j < 4; ++j) {
    const int p = wid * 32 + j * 8 + sub;
    if (mask[n_base + p]) {
      union { __hip_bfloat162 h; unsigned u; } q0, q1, q2, q3;
      q0.h = __float22bfloat162_rn(make_float2(tile[c0 + 0][p], tile[c0 + 1][p]));
      q1.h = __float22bfloat162_rn(make_float2(tile[c0 + 2][p], tile[c0 + 3][p]));
      q2.h = __float22bfloat162_rn(make_float2(tile[c0 + 4][p], tile[c0 + 5][p]));
      q3.h = __float22bfloat162_rn(make_float2(tile[c0 + 6][p], tile[c0 + 7][p]));
      uint4 pk; pk.x = q0.u; pk.y = q1.u; pk.z = q2.u; pk.w = q3.u;
      *(uint4*)(xtb + (n_base + p) * CC + c0) = pk;
    }
  }

  // Phase B: per-position channel sum/max (wave partials over 16 channels).
#pragma unroll
  for (int rep = 0; rep < 2; ++rep) {
    const int pos = rep * 64 + lane;
    const int cc0 = wid * 16;
    float psum = tile[cc0][pos];
    float pmax = psum;
#pragma unroll
    for (int c = 1; c < 16; ++c) {
      const float v = tile[cc0 + c][pos];
      psum += v;
      pmax = fmaxf(pmax, v);
    }
    sred[wid][pos] = psum;
    mred[wid][pos] = pmax;
  }
  __syncthreads();
  if (wid < 2) {
    const int pos = wid * 64 + lane;
    if (mask[n_base + pos]) {
      float2 sm;
      sm.x = sred[0][pos] + sred[1][pos] + sred[2][pos] + sred[3][pos];
      sm.y = fmaxf(fmaxf(mred[0][pos], mred[1][pos]),
                   fmaxf(mred[2][pos], mred[3][pos]));
      stats[(size_t)b * NPOS + n_base + pos] = sm;
    }
  }
}

// ---------------------------------------------------------------------------
// Kernel 2 (fused): per block = 32 l's of one batch. (unchanged; ~40 µs
// measured via round-5 double-launch differential — near floor.)
// ---------------------------------------------------------------------------
__global__ __launch_bounds__(256) void k_gather_out(
    const __hip_bfloat16* __restrict__ xt, const float2* __restrict__ stats,
    const int* __restrict__ idx, const float* __restrict__ att_w,
    const float* __restrict__ att_b, const float* __restrict__ tc_w,
    const float* __restrict__ tc_b, float* __restrict__ out) {
  const int blk    = blockIdx.x;
  const int b      = blk / (LL / 32);
  const int l_base = (blk % (LL / 32)) * 32;
  const int t = threadIdx.x, lane = t & 63, wid = t >> 6;
  const int qw = lane >> 4;             // quarter-wave id 0..3
  const int lq = lane & 15;             // lane-in-quarter
  const int cb = lq << 2;               // channel base (4 channels per lane)
  __shared__ float  res[64][33];        // [c][l-in-block]
  __shared__ float2 nw[32][KK];         // .x = n (int bits), .y = att weight
  __shared__ float  sms[32][KK], smm[32][KK];
  __shared__ float  aw[2 * KK * KK + KK];

  if (t < 2 * KK * KK + KK)
    aw[t] = (t < 2 * KK * KK) ? att_w[t] : att_b[t - 2 * KK * KK];

  const float2* stb = stats + (size_t)b * NPOS;
  // step 1a
  for (int i = t; i < 32 * KK; i += 256) {
    const int ll = i / KK, k = i - ll * KK;
    const int n = idx[(l_base + ll) * KK + k];
    nw[ll][k].x = __int_as_float(n);
    const float2 sm = stb[n];
    sms[ll][k] = sm.x;
    smm[ll][k] = sm.y;
  }
  __syncthreads();

  // step 1b
  for (int i = t; i < 32 * KK; i += 256) {
    const int ll = i / KK, h = i - ll * KK;
    float logit = aw[2 * KK * KK + h];
#pragma unroll
    for (int k = 0; k < KK; ++k) {
      logit = fmaf(sms[ll][k] * (1.0f / 64.0f), aw[h * 2 * KK + k], logit);
      logit = fmaf(smm[ll][k], aw[h * 2 * KK + KK + k], logit);
    }
    nw[ll][h].y = 1.0f + 1.0f / (1.0f + __expf(-logit));
  }

  // per-lane tc weights for 4 owned channels (overlaps with step 1b)
  float tw[4][KK], tb[4];
#pragma unroll
  for (int i = 0; i < 4; ++i) {
#pragma unroll
    for (int k = 0; k < KK; ++k) tw[i][k] = tc_w[(cb + i) * KK + k];
    tb[i] = tc_b[cb + i];
  }
  __syncthreads();

  // step 2: weighted gather-reduce. Quarter-wave per l, 8 B/lane.
  const uint2* xtb2 = (const uint2*)xt + (size_t)b * NPOS * 16;
#pragma unroll
  for (int j = 0; j < 2; ++j) {
    const int ll = wid * 8 + j * 4 + qw;
    float2 pw[KK];
#pragma unroll
    for (int k = 0; k < KK; ++k) pw[k] = nw[ll][k];   // broadcast ds_read_b64
    uint2 u[KK];
#pragma unroll
    for (int k = 0; k < KK; ++k)
      u[k] = xtb2[(size_t)__float_as_int(pw[k].x) * 16 + lq];
    float a0 = 0.f, a1 = 0.f, a2 = 0.f, a3 = 0.f;
#pragma unroll
    for (int k = 0; k < KK; ++k) {
      const float wk = pw[k].y;
      a0 = fmaf(wk * tw[0][k], __uint_as_float(u[k].x << 16), a0);
      a1 = fmaf(wk * tw[1][k], __uint_as_float(u[k].x & 0xffff0000u), a1);
      a2 = fmaf(wk * tw[2][k], __uint_as_float(u[k].y << 16), a2);
      a3 = fmaf(wk * tw[3][k], __uint_as_float(u[k].y & 0xffff0000u), a3);
    }
    res[cb + 0][ll] = a0 + tb[0];
    res[cb + 1][ll] = a1 + tb[1];
    res[cb + 2][ll] = a2 + tb[2];
    res[cb + 3][ll] = a3 + tb[3];
  }
  __syncthreads();

  // step 3: 64c x 32l tile out, float4 per store, 2 per thread.
  const int c  = t >> 2;
  const int q4 = t & 3;
#pragma unroll
  for (int rep = 0; rep < 2; ++rep) {
    const int lo = rep * 16 + q4 * 4;
    float4 o;
    o.x = res[c][lo + 0];
    o.y = res[c][lo + 1];
    o.z = res[c][lo + 2];
    o.w = res[c][lo + 3];
    *(float4*)(out + ((size_t)b * CC + c) * LL + l_base + lo) = o;
  }
}

extern "C" void kernel_launch(void* const* d_in, const int* in_sizes, int n_in,
                              void* d_out, int out_size, void* d_ws, size_t ws_size,
                              hipStream_t stream) {
  const float* x     = (const float*)d_in[0];
  const int*   idx   = (const int*)d_in[1];
  const float* att_w = (const float*)d_in[2];
  const float* att_b = (const float*)d_in[3];
  const float* tc_w  = (const float*)d_in[4];
  const float* tc_b  = (const float*)d_in[5];
  float* out = (float*)d_out;

  // ws carve: xt bf16 (2*N*64, 168 MB) | stats float2 (2*N, 10.5 MB)
  //           | mask (N bytes, 0.65 MB)
  __hip_bfloat16* xt = (__hip_bfloat16*)d_ws;
  float2* stats = (float2*)(xt + (size_t)2 * NPOS * CC);
  unsigned char* mask = (unsigned char*)(stats + (size_t)2 * NPOS);

  k_mask_zero<<<NPOS / (16 * 256), 256, 0, stream>>>((uint4*)mask);
  k_mask_set<<<(LL * KK + 255) / 256, 256, 0, stream>>>(idx, mask);

  dim3 g1(HWSZ / HT, 2 * QQ);
  k_transpose_stats<<<g1, 256, 0, stream>>>(x, mask, xt, stats);

  dim3 g2(2 * (LL / 32));
  k_gather_out<<<g2, 256, 0, stream>>>(xt, stats, idx, att_w, att_b,
                                       tc_w, tc_b, out);
}